// Round 9
// baseline (225.316 us; speedup 1.0000x reference)
//
#include <hip/hip_runtime.h>
#include <hip/hip_bf16.h>

typedef short s16x8 __attribute__((ext_vector_type(8)));
typedef float f32x4 __attribute__((ext_vector_type(4)));

__device__ __forceinline__ float b2f(unsigned short u) {
    union { unsigned int i; float f; } v;
    v.i = ((unsigned int)u) << 16;
    return v.f;
}
// packed fp32x2 -> bf16x2 (v_cvt_pk_bf16_f32 on gfx950); lo = a, hi = b
__device__ __forceinline__ unsigned int pkbf16(float a, float b) {
    union { __hip_bfloat162 h; unsigned int u; } v;
    v.h = __float22bfloat162_rn(make_float2(a, b));
    return v.u;
}
// raw v_exp_f32 — libm exp2f adds clamp/scale VALU (measured regression r5)
__device__ __forceinline__ float fast_exp2(float x) {
#if __has_builtin(__builtin_amdgcn_exp2f)
    return __builtin_amdgcn_exp2f(x);
#else
    return exp2f(x);
#endif
}
// neighbor-swap lane^1 on the VALU pipe (DPP quad_perm [1,0,3,2]), NOT ds_swizzle
__device__ __forceinline__ float dpp_xor1(float x) {
    int i = __builtin_bit_cast(int, x);
    int y = __builtin_amdgcn_mov_dpp(i, 0xB1, 0xF, 0xF, true);
    return __builtin_bit_cast(float, y);
}

// async global->LDS, 16B/lane; LDS dest = wave-uniform base + lane*16
__device__ __forceinline__ void gl_lds16(const unsigned short* g, unsigned short* l) {
    __builtin_amdgcn_global_load_lds(
        (const __attribute__((address_space(1))) void*)g,
        (__attribute__((address_space(3))) void*)l, 16, 0, 0);
}

// XOR-swizzle: 16B block c of row r lives at physical block c^(r%8) (mod row width).

// ---------------------------------------------------------------------------
// Merged fp32->bf16 converts + bias pack, one launch.
// ---------------------------------------------------------------------------
__device__ __forceinline__ void cvt8(const float* __restrict__ s,
                                     unsigned short* __restrict__ d, int i) {
    const float* p = s + (size_t)i * 8;
    float4 a = *(const float4*)p;
    float4 b = *(const float4*)(p + 4);
    unsigned int u0 = pkbf16(a.x, a.y), u1 = pkbf16(a.z, a.w);
    unsigned int u2 = pkbf16(b.x, b.y), u3 = pkbf16(b.z, b.w);
    uint4 o = {u0, u1, u2, u3};
    *(uint4*)&d[(size_t)i * 8] = o;
}

__global__ __launch_bounds__(256) void cvt_main(
    const float* __restrict__ x,  const float* __restrict__ Wq,
    const float* __restrict__ Wk, const float* __restrict__ Wv,
    const float* __restrict__ Wr, const float* __restrict__ Ws,
    const float* __restrict__ bq, const float* __restrict__ bk,
    const float* __restrict__ bv,
    unsigned short* __restrict__ xb, unsigned short* __restrict__ wqkv,
    unsigned short* __restrict__ wg, float* __restrict__ bqkv)
{
    int blk = blockIdx.x, t = threadIdx.x;
    if (blk < 2048)      cvt8(x,  xb,             blk * 256 + t);
    else if (blk < 2560) cvt8(Wq, wqkv,           (blk - 2048) * 256 + t);
    else if (blk < 3072) cvt8(Wk, wqkv + 1048576, (blk - 2560) * 256 + t);
    else if (blk < 3584) cvt8(Wv, wqkv + 2097152, (blk - 3072) * 256 + t);
    else if (blk < 3592) { int i = (blk - 3584) * 256 + t; if (i < 1920) cvt8(Wr, wg, i); }
    else if (blk < 3593) { int i = t; cvt8(Ws, wg + 15360, i); }
    else {
        int i = (blk - 3593) * 256 + t;  // 0..3071
        bqkv[i] = (i < 1024) ? bq[i] : (i < 2048) ? bk[i - 1024] : bv[i - 2048];
    }
}

// ---------------------------------------------------------------------------
// QKV GEMM: C = xb[4096][1024] * Wqkv[3072][1024]^T + bias.
// 128x128 tile, BK=64, swizzled LDS + global_load_lds.
// n0<1024 -> Q; <2048 -> K; else V written transposed to Vt[b,h,d,tok].
// ---------------------------------------------------------------------------
__global__ __launch_bounds__(256) void qkv_gemm(
    const unsigned short* __restrict__ A,
    const unsigned short* __restrict__ Bw,
    const float* __restrict__ bias,
    unsigned short* __restrict__ Q, unsigned short* __restrict__ K,
    unsigned short* __restrict__ Vt)
{
    __shared__ __attribute__((aligned(16))) unsigned short As[128 * 64];
    __shared__ __attribute__((aligned(16))) unsigned short Bs[128 * 64];
    const int t = threadIdx.x;
    const int wave = t >> 6, lane = t & 63;
    const int m0 = blockIdx.x * 128, n0 = blockIdx.y * 128;
    const int wm = (wave >> 1) * 64, wn = (wave & 1) * 64;
    const int lr = lane & 15, lq = lane >> 4;
    const int srow = lane >> 3;
    const int scol = (((lane & 7) ^ srow) << 3);

    f32x4 acc[4][4];
#pragma unroll
    for (int i = 0; i < 4; ++i)
#pragma unroll
        for (int j = 0; j < 4; ++j) acc[i][j] = (f32x4){0.f, 0.f, 0.f, 0.f};

    for (int k0 = 0; k0 < 1024; k0 += 64) {
        __syncthreads();
#pragma unroll
        for (int i = 0; i < 4; ++i) {
            int rb = wave * 32 + i * 8;
            gl_lds16(&A[(size_t)(m0 + rb + srow) * 1024 + k0 + scol], &As[rb * 64]);
            gl_lds16(&Bw[(size_t)(n0 + rb + srow) * 1024 + k0 + scol], &Bs[rb * 64]);
        }
        __syncthreads();
#pragma unroll
        for (int kk = 0; kk < 64; kk += 32) {
            const int po = ((((kk >> 3) + lq) ^ (lr & 7)) << 3);
            s16x8 af[4], bf[4];
#pragma unroll
            for (int i = 0; i < 4; ++i)
                af[i] = *(const s16x8*)&As[(wm + i * 16 + lr) * 64 + po];
#pragma unroll
            for (int j = 0; j < 4; ++j)
                bf[j] = *(const s16x8*)&Bs[(wn + j * 16 + lr) * 64 + po];
#pragma unroll
            for (int i = 0; i < 4; ++i)
#pragma unroll
                for (int j = 0; j < 4; ++j)
                    acc[i][j] = __builtin_amdgcn_mfma_f32_16x16x32_bf16(af[i], bf[j], acc[i][j], 0, 0, 0);
        }
    }
    const int kind = n0 >> 10;        // 0=Q 1=K 2=V
    const int nc = n0 & 1023;
    if (kind < 2) {
        unsigned short* Cm = kind ? K : Q;
#pragma unroll
        for (int j = 0; j < 4; ++j) {
            int cl = wn + j * 16 + lr;
            float bv = bias[n0 + cl];
#pragma unroll
            for (int i = 0; i < 4; ++i) {
                int rowb = m0 + wm + i * 16 + lq * 4;
                unsigned int u0 = pkbf16(acc[i][j][0] + bv, acc[i][j][1] + bv);
                unsigned int u1 = pkbf16(acc[i][j][2] + bv, acc[i][j][3] + bv);
                Cm[(size_t)(rowb + 0) * 1024 + nc + cl] = (unsigned short)u0;
                Cm[(size_t)(rowb + 1) * 1024 + nc + cl] = (unsigned short)(u0 >> 16);
                Cm[(size_t)(rowb + 2) * 1024 + nc + cl] = (unsigned short)u1;
                Cm[(size_t)(rowb + 3) * 1024 + nc + cl] = (unsigned short)(u1 >> 16);
            }
        }
    } else {
        // V -> Vt[b,h,d,tok]: 4 consecutive tokens per lane = 8B contiguous
        const int bb = m0 >> 11;
#pragma unroll
        for (int j = 0; j < 4; ++j) {
            int col = nc + wn + j * 16 + lr;      // channel 0..1023
            int hh = col >> 6, dd = col & 63;
            float bv = bias[n0 + wn + j * 16 + lr];
#pragma unroll
            for (int i = 0; i < 4; ++i) {
                int tokb = m0 + wm + i * 16 + lq * 4;
                int tloc = tokb & 2047;
                uint2 u;
                u.x = pkbf16(acc[i][j][0] + bv, acc[i][j][1] + bv);
                u.y = pkbf16(acc[i][j][2] + bv, acc[i][j][3] + bv);
                *(uint2*)&Vt[((size_t)(bb * 16 + hh) * 64 + dd) * 2048 + tloc] = u;
            }
        }
    }
}

// ---------------------------------------------------------------------------
// Flash attention, 128-q tile, Q-fragments in registers (q-scale fused),
// 128-key staging chunks in two 64-key halves, m=0 softmax, deferred
// l-reduce, swizzled LDS. Ps writes: DPP neighbor-swap -> paired b32 stores
// (halves LDS write-pipe ops; layout/values identical).
// Grid (bh=32, qtile=16): one head's q-tiles share an XCD -> K/V L2 locality.
// ---------------------------------------------------------------------------
__global__ __launch_bounds__(256) void attn_kernel(
    const unsigned short* __restrict__ Q,   // raw q [B*N][C]
    const unsigned short* __restrict__ Kb,  // [B*N][C]
    const unsigned short* __restrict__ Vt,  // [B][H][64][N]
    const float* __restrict__ temp,
    const float* __restrict__ qe,
    unsigned short* __restrict__ Hout)      // [B*N][C]
{
    __shared__ __attribute__((aligned(16))) unsigned short Ks[128 * 64];  // 16 KB (also Q staging)
    __shared__ __attribute__((aligned(16))) unsigned short Vs[64 * 128];  // 16 KB
    __shared__ __attribute__((aligned(16))) unsigned short Ps[128 * 72];  // 18 KB
    const int t = threadIdx.x, wave = t >> 6, lane = t & 63;
    const int lr = lane & 15, lq = lane >> 4;
    const int bh = blockIdx.x, b = bh >> 4, h = bh & 15;
    const int q0 = blockIdx.y * 128;
    const int srow = lane >> 3;
    const int scol = (((lane & 7) ^ srow) << 3);
    // paired-write key offsets (even lanes: j=0,1 pairs; odd lanes: j=2,3 pairs)
    const int par = lr & 1;
    const int kw0 = par ? (31 + lr) : lr;          // first key of pair, write 0
    const int kw1 = par ? (47 + lr) : (16 + lr);   // first key of pair, write 1

    // ---- prologue: stage raw Q (swizzled) into Ks region
#pragma unroll
    for (int i = 0; i < 4; ++i) {
        int rb = wave * 32 + i * 8;
        gl_lds16(&Q[(size_t)(b * 2048 + q0 + rb + srow) * 1024 + h * 64 + scol], &Ks[rb * 64]);
    }
    __syncthreads();

    // q' = (q/||q|| + qe[h]) * softplus(temp[h]) / (8 ln2), into registers.
    float tv = temp[h];
    float sp = ((tv > 20.f) ? tv : log1pf(__expf(tv))) * 0.18033688f;
    s16x8 aq[2][2];
#pragma unroll
    for (int i = 0; i < 2; ++i) {
        float v[2][8];
        float ss = 0.f;
#pragma unroll
        for (int kk = 0; kk < 2; ++kk) {
            const int po = (((kk * 4 + lq) ^ (lr & 7)) << 3);
            s16x8 f = *(const s16x8*)&Ks[(wave * 32 + i * 16 + lr) * 64 + po];
#pragma unroll
            for (int e = 0; e < 8; ++e) {
                v[kk][e] = b2f((unsigned short)f[e]);
                ss += v[kk][e] * v[kk][e];
            }
        }
        ss += __shfl_xor(ss, 16); ss += __shfl_xor(ss, 32);
        float rn = rsqrtf(ss);
#pragma unroll
        for (int kk = 0; kk < 2; ++kk) {
            const float* qh = qe + h * 64 + kk * 32 + lq * 8;
#pragma unroll
            for (int e = 0; e < 8; e += 2) {
                unsigned int u = pkbf16((v[kk][e] * rn + qh[e]) * sp,
                                        (v[kk][e + 1] * rn + qh[e + 1]) * sp);
                aq[i][kk][e] = (short)u; aq[i][kk][e + 1] = (short)(u >> 16);
            }
        }
    }

    f32x4 accO[2][4];
#pragma unroll
    for (int i = 0; i < 2; ++i)
#pragma unroll
        for (int j = 0; j < 4; ++j) accO[i][j] = (f32x4){0.f, 0.f, 0.f, 0.f};
    float lsum[2][4] = {{0.f, 0.f, 0.f, 0.f}, {0.f, 0.f, 0.f, 0.f}};

    for (int kc = 0; kc < 2048; kc += 128) {
        __syncthreads();  // prior reads (Q-frags on iter 0 / K,V on others) done
        // stage K: 128 key-rows x 64 d (wave stages 32 rows)
#pragma unroll
        for (int i = 0; i < 4; ++i) {
            int rb = wave * 32 + i * 8;
            gl_lds16(&Kb[(size_t)(b * 2048 + kc + rb + srow) * 1024 + h * 64 + scol], &Ks[rb * 64]);
        }
        // stage V: 64 d-rows x 128 keys (wave stages 16 rows; 4 rows/instr)
#pragma unroll
        for (int i = 0; i < 4; ++i) {
            int rb = wave * 16 + i * 4;
            int vrow = rb + (lane >> 4);
            int vcb = lane & 15;
            gl_lds16(&Vt[((size_t)(b * 16 + h) * 64 + vrow) * 2048 + kc + ((vcb ^ (vrow & 7)) << 3)],
                     &Vs[rb * 128]);
        }
        __syncthreads();

#pragma unroll
        for (int half = 0; half < 2; ++half) {
            // S = Q*K^T (32 q-rows x 64 keys per wave)
            f32x4 s[2][4];
#pragma unroll
            for (int i = 0; i < 2; ++i)
#pragma unroll
                for (int j = 0; j < 4; ++j) s[i][j] = (f32x4){0.f, 0.f, 0.f, 0.f};
#pragma unroll
            for (int kk = 0; kk < 2; ++kk) {
                const int po = (((kk * 4 + lq) ^ (lr & 7)) << 3);
                s16x8 bk[4];
#pragma unroll
                for (int j = 0; j < 4; ++j)
                    bk[j] = *(const s16x8*)&Ks[(half * 64 + j * 16 + lr) * 64 + po];
#pragma unroll
                for (int i = 0; i < 2; ++i)
#pragma unroll
                    for (int j = 0; j < 4; ++j)
                        s[i][j] = __builtin_amdgcn_mfma_f32_16x16x32_bf16(aq[i][kk], bk[j], s[i][j], 0, 0, 0);
            }

            // p = 2^s; DPP neighbor-swap -> paired b32 Ps stores
#pragma unroll
            for (int i = 0; i < 2; ++i)
#pragma unroll
                for (int r = 0; r < 4; ++r) {
                    float p0 = fast_exp2(s[i][0][r]), p1 = fast_exp2(s[i][1][r]);
                    float p2 = fast_exp2(s[i][2][r]), p3 = fast_exp2(s[i][3][r]);
                    lsum[i][r] += (p0 + p1) + (p2 + p3);
                    float n0 = dpp_xor1(p0), n1 = dpp_xor1(p1);
                    float n2 = dpp_xor1(p2), n3 = dpp_xor1(p3);
                    // even lane: (p0,n0)=keys(lr,lr+1), (p1,n1)=keys(16+lr,+1)
                    // odd lane:  (n2,p2)=keys(31+lr,32+lr), (n3,p3)=keys(47+lr,48+lr)
                    float lo0 = par ? n2 : p0, hi0 = par ? p2 : n0;
                    float lo1 = par ? n3 : p1, hi1 = par ? p3 : n1;
                    int rowb = (wave * 32 + i * 16 + lq * 4 + r) * 72;
                    *(unsigned int*)&Ps[rowb + kw0] = pkbf16(lo0, hi0);
                    *(unsigned int*)&Ps[rowb + kw1] = pkbf16(lo1, hi1);
                }

            // O += P * V  (same-wave LDS ordering; no barrier)
#pragma unroll
            for (int kk = 0; kk < 2; ++kk) {
                const int vb = (((half * 8 + kk * 4 + lq) ^ (lr & 7)) << 3);
                s16x8 ap[2], bv[4];
#pragma unroll
                for (int i = 0; i < 2; ++i)
                    ap[i] = *(const s16x8*)&Ps[(wave * 32 + i * 16 + lr) * 72 + kk * 32 + lq * 8];
#pragma unroll
                for (int j = 0; j < 4; ++j)
                    bv[j] = *(const s16x8*)&Vs[(j * 16 + lr) * 128 + vb];
#pragma unroll
                for (int i = 0; i < 2; ++i)
#pragma unroll
                    for (int j = 0; j < 4; ++j)
                        accO[i][j] = __builtin_amdgcn_mfma_f32_16x16x32_bf16(ap[i], bv[j], accO[i][j], 0, 0, 0);
            }
        }
    }

#pragma unroll
    for (int i = 0; i < 2; ++i)
#pragma unroll
        for (int r = 0; r < 4; ++r) {
            float l = lsum[i][r];
            l += __shfl_xor(l, 1); l += __shfl_xor(l, 2);
            l += __shfl_xor(l, 4); l += __shfl_xor(l, 8);
            float inv = 1.f / l;
            int row = q0 + wave * 32 + i * 16 + lq * 4 + r;
            size_t ob = (size_t)(b * 2048 + row) * 1024 + h * 64 + lr;
            unsigned int u0 = pkbf16(accO[i][0][r] * inv, accO[i][1][r] * inv);
            unsigned int u1 = pkbf16(accO[i][2][r] * inv, accO[i][3][r] * inv);
            Hout[ob]      = (unsigned short)u0;
            Hout[ob + 16] = (unsigned short)(u0 >> 16);
            Hout[ob + 32] = (unsigned short)u1;
            Hout[ob + 48] = (unsigned short)(u1 >> 16);
        }
}

// ---------------------------------------------------------------------------
// gate_g: g[tok] = 2*sw0 + 6*sw1*top3sum from logits = h*Wg^T + bias.
// Side job: converts Wp fp32->bf16 into wpb (region free after attn) —
// removes the standalone cvt dispatch.
// ---------------------------------------------------------------------------
__global__ __launch_bounds__(256) void gate_g(
    const unsigned short* __restrict__ Hb,   // raw h [4096][1024]
    const unsigned short* __restrict__ Wg,   // rows 0..16 bf16
    const float* __restrict__ br, const float* __restrict__ bs,
    const float* __restrict__ Wp, unsigned short* __restrict__ wpb,
    float* __restrict__ g)
{
    __shared__ __attribute__((aligned(16))) unsigned short As[4][16 * 64];
    __shared__ __attribute__((aligned(16))) unsigned short Gs[4][32 * 64];
    __shared__ float Lred[4][16][32];
    const int t = threadIdx.x, wave = t >> 6, lane = t & 63;
    const int lr = lane & 15, lq = lane >> 4;
    const int m0 = blockIdx.x * 16;
    const int srow = lane >> 3;
    const int scol = (((lane & 7) ^ srow) << 3);

    // Wp convert side-job: 512 cvt8 units per block (131072 total / 256 blocks)
    cvt8(Wp, wpb, blockIdx.x * 512 + t);
    cvt8(Wp, wpb, blockIdx.x * 512 + 256 + t);

    f32x4 acc[2];
    acc[0] = (f32x4){0.f, 0.f, 0.f, 0.f};
    acc[1] = (f32x4){0.f, 0.f, 0.f, 0.f};

    for (int k0 = wave * 64; k0 < 1024; k0 += 256) {
        gl_lds16(&Hb[(size_t)(m0 + srow) * 1024 + k0 + scol], &As[wave][0]);
        gl_lds16(&Hb[(size_t)(m0 + 8 + srow) * 1024 + k0 + scol], &As[wave][8 * 64]);
#pragma unroll
        for (int i = 0; i < 4; ++i) {
            int row = i * 8 + srow;
            int wr = (row > 16) ? 16 : row;   // clamp: no OOB
            gl_lds16(&Wg[(size_t)wr * 1024 + k0 + scol], &Gs[wave][i * 8 * 64]);
        }
        __syncthreads();   // uniform trip count across waves
#pragma unroll
        for (int kk = 0; kk < 64; kk += 32) {
            const int po = ((((kk >> 3) + lq) ^ (lr & 7)) << 3);
            s16x8 af = *(const s16x8*)&As[wave][lr * 64 + po];
#pragma unroll
            for (int j = 0; j < 2; ++j) {
                s16x8 gf = *(const s16x8*)&Gs[wave][(j * 16 + lr) * 64 + po];
                acc[j] = __builtin_amdgcn_mfma_f32_16x16x32_bf16(af, gf, acc[j], 0, 0, 0);
            }
        }
    }
#pragma unroll
    for (int j = 0; j < 2; ++j)
#pragma unroll
        for (int r = 0; r < 4; ++r)
            Lred[wave][lq * 4 + r][j * 16 + lr] = acc[j][r];
    __syncthreads();
    if (t < 16) {
        float lg[17];
#pragma unroll
        for (int j = 0; j < 17; ++j)
            lg[j] = Lred[0][t][j] + Lred[1][t][j] + Lred[2][t][j] + Lred[3][t][j]
                  + ((j < 15) ? br[j] : bs[j - 15]);
        float mx = lg[0];
#pragma unroll
        for (int j = 1; j < 15; ++j) mx = fmaxf(mx, lg[j]);
        float sum = 0.f, v1 = -1.f, v2 = -1.f, v3 = -1.f;
#pragma unroll
        for (int j = 0; j < 15; ++j) {
            float e = __expf(lg[j] - mx);
            sum += e;
            if (e > v1)      { v3 = v2; v2 = v1; v1 = e; }
            else if (e > v2) { v3 = v2; v2 = e; }
            else if (e > v3) { v3 = e; }
        }
        float tops = (v1 + v2 + v3) / sum;
        float sm = fmaxf(lg[15], lg[16]);
        float e0 = __expf(lg[15] - sm), e1 = __expf(lg[16] - sm);
        float inv = 1.f / (e0 + e1);
        g[m0 + t] = 2.f * (e0 * inv) + 6.f * (e1 * inv) * tops;
    }
}

// ---------------------------------------------------------------------------
// Out-proj GEMM: out[m][:] = g[m] * (h·Wp^T)[m][:] + bp   (row-scale commutes)
// 64x64 tile, grid 1024 = 4 blocks/CU; 2x2 waves of 32x32.
// ---------------------------------------------------------------------------
__global__ __launch_bounds__(256) void gemm64_out(
    const unsigned short* __restrict__ A,
    const unsigned short* __restrict__ Bw,
    const float* __restrict__ bias,
    const float* __restrict__ g,
    float* __restrict__ C)
{
    __shared__ __attribute__((aligned(16))) unsigned short As[64 * 64];
    __shared__ __attribute__((aligned(16))) unsigned short Bs[64 * 64];
    const int t = threadIdx.x, wave = t >> 6, lane = t & 63;
    const int lr = lane & 15, lq = lane >> 4;
    const int m0 = blockIdx.x * 64, n0 = blockIdx.y * 64;
    const int wm = (wave >> 1) * 32, wn = (wave & 1) * 32;
    const int srow = lane >> 3;
    const int scol = (((lane & 7) ^ srow) << 3);

    f32x4 acc[2][2];
#pragma unroll
    for (int i = 0; i < 2; ++i)
#pragma unroll
        for (int j = 0; j < 2; ++j) acc[i][j] = (f32x4){0.f, 0.f, 0.f, 0.f};

    for (int k0 = 0; k0 < 1024; k0 += 64) {
        __syncthreads();
#pragma unroll
        for (int i = 0; i < 2; ++i) {
            int rb = wave * 16 + i * 8;
            gl_lds16(&A[(size_t)(m0 + rb + srow) * 1024 + k0 + scol], &As[rb * 64]);
            gl_lds16(&Bw[(size_t)(n0 + rb + srow) * 1024 + k0 + scol], &Bs[rb * 64]);
        }
        __syncthreads();
#pragma unroll
        for (int kk = 0; kk < 64; kk += 32) {
            const int po = ((((kk >> 3) + lq) ^ (lr & 7)) << 3);
            s16x8 af[2], bf[2];
#pragma unroll
            for (int i = 0; i < 2; ++i)
                af[i] = *(const s16x8*)&As[(wm + i * 16 + lr) * 64 + po];
#pragma unroll
            for (int j = 0; j < 2; ++j)
                bf[j] = *(const s16x8*)&Bs[(wn + j * 16 + lr) * 64 + po];
#pragma unroll
            for (int i = 0; i < 2; ++i)
#pragma unroll
                for (int j = 0; j < 2; ++j)
                    acc[i][j] = __builtin_amdgcn_mfma_f32_16x16x32_bf16(af[i], bf[j], acc[i][j], 0, 0, 0);
        }
    }
#pragma unroll
    for (int i = 0; i < 2; ++i) {
        const float4 gi = *(const float4*)&g[m0 + wm + i * 16 + lq * 4];
        float gv[4] = {gi.x, gi.y, gi.z, gi.w};
#pragma unroll
        for (int j = 0; j < 2; ++j) {
            int col = n0 + wn + j * 16 + lr;
            float bv = bias[col];
            int rowb = m0 + wm + i * 16 + lq * 4;
#pragma unroll
            for (int r = 0; r < 4; ++r)
                C[(size_t)(rowb + r) * 1024 + col] = acc[i][j][r] * gv[r] + bv;
        }
    }
}

// ---------------------------------------------------------------------------
extern "C" void kernel_launch(void* const* d_in, const int* in_sizes, int n_in,
                              void* d_out, int out_size, void* d_ws, size_t ws_size,
                              hipStream_t stream)
{
    (void)in_sizes; (void)n_in; (void)out_size; (void)ws_size;
    const float* x   = (const float*)d_in[0];
    const float* Wq  = (const float*)d_in[1];
    const float* bq  = (const float*)d_in[2];
    const float* Wk  = (const float*)d_in[3];
    const float* bk  = (const float*)d_in[4];
    const float* Wv  = (const float*)d_in[5];
    const float* bv  = (const float*)d_in[6];
    const float* Wp  = (const float*)d_in[7];
    const float* bp  = (const float*)d_in[8];
    const float* Wr  = (const float*)d_in[9];
    const float* br  = (const float*)d_in[10];
    const float* Ws  = (const float*)d_in[11];
    const float* bs  = (const float*)d_in[12];
    const float* temperature = (const float*)d_in[13];
    const float* qe  = (const float*)d_in[14];
    float* out = (float*)d_out;

    const size_t MB = 1048576;
    unsigned short* qb   = (unsigned short*)d_ws;                     // 8 MiB (q; wpb after attn)
    unsigned short* kb   = (unsigned short*)((char*)d_ws + 8 * MB);   // 8 MiB
    unsigned short* hb   = (unsigned short*)((char*)d_ws + 16 * MB);  // 8 MiB (raw h)
    unsigned short* wqkv = (unsigned short*)((char*)d_ws + 24 * MB);  // 6 MiB
    unsigned short* wg   = (unsigned short*)((char*)d_ws + 30 * MB);  // 34 KiB
    float*          bqkv = (float*)((char*)d_ws + 30 * MB + 65536);   // 12 KiB
    float*          gbuf = (float*)((char*)d_ws + 30 * MB + 131072);  // 16 KiB
    // d_out doubles as scratch until the final GEMM:
    unsigned short* xb = (unsigned short*)d_out;                      // 8 MiB
    unsigned short* vt = xb + 4 * MB;                                 // 8 MiB V^T
    unsigned short* wpb = qb;                                         // Wp bf16 (qb dead after attn)

    dim3 blk(256);
    cvt_main<<<dim3(3605), blk, 0, stream>>>(x, Wq, Wk, Wv, Wr, Ws, bq, bk, bv,
                                             xb, wqkv, wg, bqkv);
    qkv_gemm<<<dim3(32, 24), blk, 0, stream>>>(xb, wqkv, bqkv, qb, kb, vt);
    attn_kernel<<<dim3(32, 16), blk, 0, stream>>>(qb, kb, vt, temperature, qe, hb);
    gate_g<<<dim3(256), blk, 0, stream>>>(hb, wg, br, bs, Wp, wpb, gbuf);
    gemm64_out<<<dim3(64, 16), blk, 0, stream>>>(hb, wpb, bp, gbuf, out);
}

// Round 10
// 216.126 us; speedup vs baseline: 1.0425x; 1.0425x over previous
//
#include <hip/hip_runtime.h>
#include <hip/hip_bf16.h>

typedef short s16x8 __attribute__((ext_vector_type(8)));
typedef float f32x4 __attribute__((ext_vector_type(4)));

__device__ __forceinline__ float b2f(unsigned short u) {
    union { unsigned int i; float f; } v;
    v.i = ((unsigned int)u) << 16;
    return v.f;
}
// packed fp32x2 -> bf16x2 (v_cvt_pk_bf16_f32 on gfx950); lo = a, hi = b
__device__ __forceinline__ unsigned int pkbf16(float a, float b) {
    union { __hip_bfloat162 h; unsigned int u; } v;
    v.h = __float22bfloat162_rn(make_float2(a, b));
    return v.u;
}
// raw v_exp_f32 — libm exp2f adds clamp/scale VALU (measured regression r5)
__device__ __forceinline__ float fast_exp2(float x) {
#if __has_builtin(__builtin_amdgcn_exp2f)
    return __builtin_amdgcn_exp2f(x);
#else
    return exp2f(x);
#endif
}

// async global->LDS, 16B/lane; LDS dest = wave-uniform base + lane*16
__device__ __forceinline__ void gl_lds16(const unsigned short* g, unsigned short* l) {
    __builtin_amdgcn_global_load_lds(
        (const __attribute__((address_space(1))) void*)g,
        (__attribute__((address_space(3))) void*)l, 16, 0, 0);
}

// XOR-swizzle: 16B block c of row r lives at physical block c^(r%8) (mod row width).
// NOTE (r9 post-mortem): keep Ps stores as plain b16 — DPP-paired b32 stores
// measured WORSE (conflicts 3.1e6->5.2e6, VALUBusy +12pt, attn +9us).

// ---------------------------------------------------------------------------
// Merged fp32->bf16 converts + bias pack, one launch.
// ---------------------------------------------------------------------------
__device__ __forceinline__ void cvt8(const float* __restrict__ s,
                                     unsigned short* __restrict__ d, int i) {
    const float* p = s + (size_t)i * 8;
    float4 a = *(const float4*)p;
    float4 b = *(const float4*)(p + 4);
    unsigned int u0 = pkbf16(a.x, a.y), u1 = pkbf16(a.z, a.w);
    unsigned int u2 = pkbf16(b.x, b.y), u3 = pkbf16(b.z, b.w);
    uint4 o = {u0, u1, u2, u3};
    *(uint4*)&d[(size_t)i * 8] = o;
}

__global__ __launch_bounds__(256) void cvt_main(
    const float* __restrict__ x,  const float* __restrict__ Wq,
    const float* __restrict__ Wk, const float* __restrict__ Wv,
    const float* __restrict__ Wr, const float* __restrict__ Ws,
    const float* __restrict__ bq, const float* __restrict__ bk,
    const float* __restrict__ bv,
    unsigned short* __restrict__ xb, unsigned short* __restrict__ wqkv,
    unsigned short* __restrict__ wg, float* __restrict__ bqkv)
{
    int blk = blockIdx.x, t = threadIdx.x;
    if (blk < 2048)      cvt8(x,  xb,             blk * 256 + t);
    else if (blk < 2560) cvt8(Wq, wqkv,           (blk - 2048) * 256 + t);
    else if (blk < 3072) cvt8(Wk, wqkv + 1048576, (blk - 2560) * 256 + t);
    else if (blk < 3584) cvt8(Wv, wqkv + 2097152, (blk - 3072) * 256 + t);
    else if (blk < 3592) { int i = (blk - 3584) * 256 + t; if (i < 1920) cvt8(Wr, wg, i); }
    else if (blk < 3593) { int i = t; cvt8(Ws, wg + 15360, i); }
    else {
        int i = (blk - 3593) * 256 + t;  // 0..3071
        bqkv[i] = (i < 1024) ? bq[i] : (i < 2048) ? bk[i - 1024] : bv[i - 2048];
    }
}

// ---------------------------------------------------------------------------
// QKV GEMM: C = xb[4096][1024] * Wqkv[3072][1024]^T + bias.
// 128x128 tile, BK=64, swizzled LDS + global_load_lds.
// n0<1024 -> Q; <2048 -> K; else V written transposed to Vt[b,h,d,tok].
// ---------------------------------------------------------------------------
__global__ __launch_bounds__(256) void qkv_gemm(
    const unsigned short* __restrict__ A,
    const unsigned short* __restrict__ Bw,
    const float* __restrict__ bias,
    unsigned short* __restrict__ Q, unsigned short* __restrict__ K,
    unsigned short* __restrict__ Vt)
{
    __shared__ __attribute__((aligned(16))) unsigned short As[128 * 64];
    __shared__ __attribute__((aligned(16))) unsigned short Bs[128 * 64];
    const int t = threadIdx.x;
    const int wave = t >> 6, lane = t & 63;
    const int m0 = blockIdx.x * 128, n0 = blockIdx.y * 128;
    const int wm = (wave >> 1) * 64, wn = (wave & 1) * 64;
    const int lr = lane & 15, lq = lane >> 4;
    const int srow = lane >> 3;
    const int scol = (((lane & 7) ^ srow) << 3);

    f32x4 acc[4][4];
#pragma unroll
    for (int i = 0; i < 4; ++i)
#pragma unroll
        for (int j = 0; j < 4; ++j) acc[i][j] = (f32x4){0.f, 0.f, 0.f, 0.f};

    for (int k0 = 0; k0 < 1024; k0 += 64) {
        __syncthreads();
#pragma unroll
        for (int i = 0; i < 4; ++i) {
            int rb = wave * 32 + i * 8;
            gl_lds16(&A[(size_t)(m0 + rb + srow) * 1024 + k0 + scol], &As[rb * 64]);
            gl_lds16(&Bw[(size_t)(n0 + rb + srow) * 1024 + k0 + scol], &Bs[rb * 64]);
        }
        __syncthreads();
#pragma unroll
        for (int kk = 0; kk < 64; kk += 32) {
            const int po = ((((kk >> 3) + lq) ^ (lr & 7)) << 3);
            s16x8 af[4], bf[4];
#pragma unroll
            for (int i = 0; i < 4; ++i)
                af[i] = *(const s16x8*)&As[(wm + i * 16 + lr) * 64 + po];
#pragma unroll
            for (int j = 0; j < 4; ++j)
                bf[j] = *(const s16x8*)&Bs[(wn + j * 16 + lr) * 64 + po];
#pragma unroll
            for (int i = 0; i < 4; ++i)
#pragma unroll
                for (int j = 0; j < 4; ++j)
                    acc[i][j] = __builtin_amdgcn_mfma_f32_16x16x32_bf16(af[i], bf[j], acc[i][j], 0, 0, 0);
        }
    }
    const int kind = n0 >> 10;        // 0=Q 1=K 2=V
    const int nc = n0 & 1023;
    if (kind < 2) {
        unsigned short* Cm = kind ? K : Q;
#pragma unroll
        for (int j = 0; j < 4; ++j) {
            int cl = wn + j * 16 + lr;
            float bv = bias[n0 + cl];
#pragma unroll
            for (int i = 0; i < 4; ++i) {
                int rowb = m0 + wm + i * 16 + lq * 4;
                unsigned int u0 = pkbf16(acc[i][j][0] + bv, acc[i][j][1] + bv);
                unsigned int u1 = pkbf16(acc[i][j][2] + bv, acc[i][j][3] + bv);
                Cm[(size_t)(rowb + 0) * 1024 + nc + cl] = (unsigned short)u0;
                Cm[(size_t)(rowb + 1) * 1024 + nc + cl] = (unsigned short)(u0 >> 16);
                Cm[(size_t)(rowb + 2) * 1024 + nc + cl] = (unsigned short)u1;
                Cm[(size_t)(rowb + 3) * 1024 + nc + cl] = (unsigned short)(u1 >> 16);
            }
        }
    } else {
        // V -> Vt[b,h,d,tok]: 4 consecutive tokens per lane = 8B contiguous
        const int bb = m0 >> 11;
#pragma unroll
        for (int j = 0; j < 4; ++j) {
            int col = nc + wn + j * 16 + lr;      // channel 0..1023
            int hh = col >> 6, dd = col & 63;
            float bv = bias[n0 + wn + j * 16 + lr];
#pragma unroll
            for (int i = 0; i < 4; ++i) {
                int tokb = m0 + wm + i * 16 + lq * 4;
                int tloc = tokb & 2047;
                uint2 u;
                u.x = pkbf16(acc[i][j][0] + bv, acc[i][j][1] + bv);
                u.y = pkbf16(acc[i][j][2] + bv, acc[i][j][3] + bv);
                *(uint2*)&Vt[((size_t)(bb * 16 + hh) * 64 + dd) * 2048 + tloc] = u;
            }
        }
    }
}

// ---------------------------------------------------------------------------
// Flash attention (round-8 proven body), 128-q tile, Q-fragments in registers
// (q-scale fused), 128-key staging chunks in two 64-key halves, m=0 softmax,
// deferred l-reduce, swizzled LDS, Ps wave-private with plain b16 stores.
// Grid (bh=32, qtile=16): one head's q-tiles share an XCD -> K/V L2 locality.
// ---------------------------------------------------------------------------
__global__ __launch_bounds__(256) void attn_kernel(
    const unsigned short* __restrict__ Q,   // raw q [B*N][C]
    const unsigned short* __restrict__ Kb,  // [B*N][C]
    const unsigned short* __restrict__ Vt,  // [B][H][64][N]
    const float* __restrict__ temp,
    const float* __restrict__ qe,
    unsigned short* __restrict__ Hout)      // [B*N][C]
{
    __shared__ __attribute__((aligned(16))) unsigned short Ks[128 * 64];  // 16 KB (also Q staging)
    __shared__ __attribute__((aligned(16))) unsigned short Vs[64 * 128];  // 16 KB
    __shared__ __attribute__((aligned(16))) unsigned short Ps[128 * 72];  // 18 KB
    const int t = threadIdx.x, wave = t >> 6, lane = t & 63;
    const int lr = lane & 15, lq = lane >> 4;
    const int bh = blockIdx.x, b = bh >> 4, h = bh & 15;
    const int q0 = blockIdx.y * 128;
    const int srow = lane >> 3;
    const int scol = (((lane & 7) ^ srow) << 3);

    // ---- prologue: stage raw Q (swizzled) into Ks region
#pragma unroll
    for (int i = 0; i < 4; ++i) {
        int rb = wave * 32 + i * 8;
        gl_lds16(&Q[(size_t)(b * 2048 + q0 + rb + srow) * 1024 + h * 64 + scol], &Ks[rb * 64]);
    }
    __syncthreads();

    // q' = (q/||q|| + qe[h]) * softplus(temp[h]) / (8 ln2), into registers.
    float tv = temp[h];
    float sp = ((tv > 20.f) ? tv : log1pf(__expf(tv))) * 0.18033688f;
    s16x8 aq[2][2];
#pragma unroll
    for (int i = 0; i < 2; ++i) {
        float v[2][8];
        float ss = 0.f;
#pragma unroll
        for (int kk = 0; kk < 2; ++kk) {
            const int po = (((kk * 4 + lq) ^ (lr & 7)) << 3);
            s16x8 f = *(const s16x8*)&Ks[(wave * 32 + i * 16 + lr) * 64 + po];
#pragma unroll
            for (int e = 0; e < 8; ++e) {
                v[kk][e] = b2f((unsigned short)f[e]);
                ss += v[kk][e] * v[kk][e];
            }
        }
        ss += __shfl_xor(ss, 16); ss += __shfl_xor(ss, 32);
        float rn = rsqrtf(ss);
#pragma unroll
        for (int kk = 0; kk < 2; ++kk) {
            const float* qh = qe + h * 64 + kk * 32 + lq * 8;
#pragma unroll
            for (int e = 0; e < 8; e += 2) {
                unsigned int u = pkbf16((v[kk][e] * rn + qh[e]) * sp,
                                        (v[kk][e + 1] * rn + qh[e + 1]) * sp);
                aq[i][kk][e] = (short)u; aq[i][kk][e + 1] = (short)(u >> 16);
            }
        }
    }

    f32x4 accO[2][4];
#pragma unroll
    for (int i = 0; i < 2; ++i)
#pragma unroll
        for (int j = 0; j < 4; ++j) accO[i][j] = (f32x4){0.f, 0.f, 0.f, 0.f};
    float lsum[2][4] = {{0.f, 0.f, 0.f, 0.f}, {0.f, 0.f, 0.f, 0.f}};

    for (int kc = 0; kc < 2048; kc += 128) {
        __syncthreads();  // prior reads (Q-frags on iter 0 / K,V on others) done
        // stage K: 128 key-rows x 64 d (wave stages 32 rows)
#pragma unroll
        for (int i = 0; i < 4; ++i) {
            int rb = wave * 32 + i * 8;
            gl_lds16(&Kb[(size_t)(b * 2048 + kc + rb + srow) * 1024 + h * 64 + scol], &Ks[rb * 64]);
        }
        // stage V: 64 d-rows x 128 keys (wave stages 16 rows; 4 rows/instr)
#pragma unroll
        for (int i = 0; i < 4; ++i) {
            int rb = wave * 16 + i * 4;
            int vrow = rb + (lane >> 4);
            int vcb = lane & 15;
            gl_lds16(&Vt[((size_t)(b * 16 + h) * 64 + vrow) * 2048 + kc + ((vcb ^ (vrow & 7)) << 3)],
                     &Vs[rb * 128]);
        }
        __syncthreads();

#pragma unroll
        for (int half = 0; half < 2; ++half) {
            // S = Q*K^T (32 q-rows x 64 keys per wave)
            f32x4 s[2][4];
#pragma unroll
            for (int i = 0; i < 2; ++i)
#pragma unroll
                for (int j = 0; j < 4; ++j) s[i][j] = (f32x4){0.f, 0.f, 0.f, 0.f};
#pragma unroll
            for (int kk = 0; kk < 2; ++kk) {
                const int po = (((kk * 4 + lq) ^ (lr & 7)) << 3);
                s16x8 bk[4];
#pragma unroll
                for (int j = 0; j < 4; ++j)
                    bk[j] = *(const s16x8*)&Ks[(half * 64 + j * 16 + lr) * 64 + po];
#pragma unroll
                for (int i = 0; i < 2; ++i)
#pragma unroll
                    for (int j = 0; j < 4; ++j)
                        s[i][j] = __builtin_amdgcn_mfma_f32_16x16x32_bf16(aq[i][kk], bk[j], s[i][j], 0, 0, 0);
            }

            // p = 2^s; packed bf16; plain b16 stores (r8 proven pattern)
#pragma unroll
            for (int i = 0; i < 2; ++i)
#pragma unroll
                for (int r = 0; r < 4; ++r) {
                    float p0 = fast_exp2(s[i][0][r]), p1 = fast_exp2(s[i][1][r]);
                    float p2 = fast_exp2(s[i][2][r]), p3 = fast_exp2(s[i][3][r]);
                    lsum[i][r] += (p0 + p1) + (p2 + p3);
                    unsigned int ua = pkbf16(p0, p1), ub = pkbf16(p2, p3);
                    int base = (wave * 32 + i * 16 + lq * 4 + r) * 72 + lr;
                    Ps[base]      = (unsigned short)ua;
                    Ps[base + 16] = (unsigned short)(ua >> 16);
                    Ps[base + 32] = (unsigned short)ub;
                    Ps[base + 48] = (unsigned short)(ub >> 16);
                }

            // O += P * V  (same-wave LDS ordering; no barrier)
#pragma unroll
            for (int kk = 0; kk < 2; ++kk) {
                const int vb = (((half * 8 + kk * 4 + lq) ^ (lr & 7)) << 3);
                s16x8 ap[2], bv[4];
#pragma unroll
                for (int i = 0; i < 2; ++i)
                    ap[i] = *(const s16x8*)&Ps[(wave * 32 + i * 16 + lr) * 72 + kk * 32 + lq * 8];
#pragma unroll
                for (int j = 0; j < 4; ++j)
                    bv[j] = *(const s16x8*)&Vs[(j * 16 + lr) * 128 + vb];
#pragma unroll
                for (int i = 0; i < 2; ++i)
#pragma unroll
                    for (int j = 0; j < 4; ++j)
                        accO[i][j] = __builtin_amdgcn_mfma_f32_16x16x32_bf16(ap[i], bv[j], accO[i][j], 0, 0, 0);
            }
        }
    }

#pragma unroll
    for (int i = 0; i < 2; ++i)
#pragma unroll
        for (int r = 0; r < 4; ++r) {
            float l = lsum[i][r];
            l += __shfl_xor(l, 1); l += __shfl_xor(l, 2);
            l += __shfl_xor(l, 4); l += __shfl_xor(l, 8);
            float inv = 1.f / l;
            int row = q0 + wave * 32 + i * 16 + lq * 4 + r;
            size_t ob = (size_t)(b * 2048 + row) * 1024 + h * 64 + lr;
            unsigned int u0 = pkbf16(accO[i][0][r] * inv, accO[i][1][r] * inv);
            unsigned int u1 = pkbf16(accO[i][2][r] * inv, accO[i][3][r] * inv);
            Hout[ob]      = (unsigned short)u0;
            Hout[ob + 16] = (unsigned short)(u0 >> 16);
            Hout[ob + 32] = (unsigned short)u1;
            Hout[ob + 48] = (unsigned short)(u1 >> 16);
        }
}

// ---------------------------------------------------------------------------
// gate_g: g[tok] = 2*sw0 + 6*sw1*top3sum from logits = h*Wg^T + bias.
// Side job: converts Wp fp32->bf16 into wpb (region free after attn).
// ---------------------------------------------------------------------------
__global__ __launch_bounds__(256) void gate_g(
    const unsigned short* __restrict__ Hb,   // raw h [4096][1024]
    const unsigned short* __restrict__ Wg,   // rows 0..16 bf16
    const float* __restrict__ br, const float* __restrict__ bs,
    const float* __restrict__ Wp, unsigned short* __restrict__ wpb,
    float* __restrict__ g)
{
    __shared__ __attribute__((aligned(16))) unsigned short As[4][16 * 64];
    __shared__ __attribute__((aligned(16))) unsigned short Gs[4][32 * 64];
    __shared__ float Lred[4][16][32];
    const int t = threadIdx.x, wave = t >> 6, lane = t & 63;
    const int lr = lane & 15, lq = lane >> 4;
    const int m0 = blockIdx.x * 16;
    const int srow = lane >> 3;
    const int scol = (((lane & 7) ^ srow) << 3);

    // Wp convert side-job: 512 cvt8 units per block (131072 total / 256 blocks)
    cvt8(Wp, wpb, blockIdx.x * 512 + t);
    cvt8(Wp, wpb, blockIdx.x * 512 + 256 + t);

    f32x4 acc[2];
    acc[0] = (f32x4){0.f, 0.f, 0.f, 0.f};
    acc[1] = (f32x4){0.f, 0.f, 0.f, 0.f};

    for (int k0 = wave * 64; k0 < 1024; k0 += 256) {
        gl_lds16(&Hb[(size_t)(m0 + srow) * 1024 + k0 + scol], &As[wave][0]);
        gl_lds16(&Hb[(size_t)(m0 + 8 + srow) * 1024 + k0 + scol], &As[wave][8 * 64]);
#pragma unroll
        for (int i = 0; i < 4; ++i) {
            int row = i * 8 + srow;
            int wr = (row > 16) ? 16 : row;   // clamp: no OOB
            gl_lds16(&Wg[(size_t)wr * 1024 + k0 + scol], &Gs[wave][i * 8 * 64]);
        }
        __syncthreads();   // uniform trip count across waves
#pragma unroll
        for (int kk = 0; kk < 64; kk += 32) {
            const int po = ((((kk >> 3) + lq) ^ (lr & 7)) << 3);
            s16x8 af = *(const s16x8*)&As[wave][lr * 64 + po];
#pragma unroll
            for (int j = 0; j < 2; ++j) {
                s16x8 gf = *(const s16x8*)&Gs[wave][(j * 16 + lr) * 64 + po];
                acc[j] = __builtin_amdgcn_mfma_f32_16x16x32_bf16(af, gf, acc[j], 0, 0, 0);
            }
        }
    }
#pragma unroll
    for (int j = 0; j < 2; ++j)
#pragma unroll
        for (int r = 0; r < 4; ++r)
            Lred[wave][lq * 4 + r][j * 16 + lr] = acc[j][r];
    __syncthreads();
    if (t < 16) {
        float lg[17];
#pragma unroll
        for (int j = 0; j < 17; ++j)
            lg[j] = Lred[0][t][j] + Lred[1][t][j] + Lred[2][t][j] + Lred[3][t][j]
                  + ((j < 15) ? br[j] : bs[j - 15]);
        float mx = lg[0];
#pragma unroll
        for (int j = 1; j < 15; ++j) mx = fmaxf(mx, lg[j]);
        float sum = 0.f, v1 = -1.f, v2 = -1.f, v3 = -1.f;
#pragma unroll
        for (int j = 0; j < 15; ++j) {
            float e = __expf(lg[j] - mx);
            sum += e;
            if (e > v1)      { v3 = v2; v2 = v1; v1 = e; }
            else if (e > v2) { v3 = v2; v2 = e; }
            else if (e > v3) { v3 = e; }
        }
        float tops = (v1 + v2 + v3) / sum;
        float sm = fmaxf(lg[15], lg[16]);
        float e0 = __expf(lg[15] - sm), e1 = __expf(lg[16] - sm);
        float inv = 1.f / (e0 + e1);
        g[m0 + t] = 2.f * (e0 * inv) + 6.f * (e1 * inv) * tops;
    }
}

// ---------------------------------------------------------------------------
// Out-proj GEMM: out[m][:] = g[m] * (h·Wp^T)[m][:] + bp   (row-scale commutes)
// 64x64 tile, grid 1024 = 4 blocks/CU; 2x2 waves of 32x32.
// ---------------------------------------------------------------------------
__global__ __launch_bounds__(256) void gemm64_out(
    const unsigned short* __restrict__ A,
    const unsigned short* __restrict__ Bw,
    const float* __restrict__ bias,
    const float* __restrict__ g,
    float* __restrict__ C)
{
    __shared__ __attribute__((aligned(16))) unsigned short As[64 * 64];
    __shared__ __attribute__((aligned(16))) unsigned short Bs[64 * 64];
    const int t = threadIdx.x, wave = t >> 6, lane = t & 63;
    const int lr = lane & 15, lq = lane >> 4;
    const int m0 = blockIdx.x * 64, n0 = blockIdx.y * 64;
    const int wm = (wave >> 1) * 32, wn = (wave & 1) * 32;
    const int srow = lane >> 3;
    const int scol = (((lane & 7) ^ srow) << 3);

    f32x4 acc[2][2];
#pragma unroll
    for (int i = 0; i < 2; ++i)
#pragma unroll
        for (int j = 0; j < 2; ++j) acc[i][j] = (f32x4){0.f, 0.f, 0.f, 0.f};

    for (int k0 = 0; k0 < 1024; k0 += 64) {
        __syncthreads();
#pragma unroll
        for (int i = 0; i < 2; ++i) {
            int rb = wave * 16 + i * 8;
            gl_lds16(&A[(size_t)(m0 + rb + srow) * 1024 + k0 + scol], &As[rb * 64]);
            gl_lds16(&Bw[(size_t)(n0 + rb + srow) * 1024 + k0 + scol], &Bs[rb * 64]);
        }
        __syncthreads();
#pragma unroll
        for (int kk = 0; kk < 64; kk += 32) {
            const int po = ((((kk >> 3) + lq) ^ (lr & 7)) << 3);
            s16x8 af[2], bf[2];
#pragma unroll
            for (int i = 0; i < 2; ++i)
                af[i] = *(const s16x8*)&As[(wm + i * 16 + lr) * 64 + po];
#pragma unroll
            for (int j = 0; j < 2; ++j)
                bf[j] = *(const s16x8*)&Bs[(wn + j * 16 + lr) * 64 + po];
#pragma unroll
            for (int i = 0; i < 2; ++i)
#pragma unroll
                for (int j = 0; j < 2; ++j)
                    acc[i][j] = __builtin_amdgcn_mfma_f32_16x16x32_bf16(af[i], bf[j], acc[i][j], 0, 0, 0);
        }
    }
#pragma unroll
    for (int i = 0; i < 2; ++i) {
        const float4 gi = *(const float4*)&g[m0 + wm + i * 16 + lq * 4];
        float gv[4] = {gi.x, gi.y, gi.z, gi.w};
#pragma unroll
        for (int j = 0; j < 2; ++j) {
            int col = n0 + wn + j * 16 + lr;
            float bv = bias[col];
            int rowb = m0 + wm + i * 16 + lq * 4;
#pragma unroll
            for (int r = 0; r < 4; ++r)
                C[(size_t)(rowb + r) * 1024 + col] = acc[i][j][r] * gv[r] + bv;
        }
    }
}

// ---------------------------------------------------------------------------
extern "C" void kernel_launch(void* const* d_in, const int* in_sizes, int n_in,
                              void* d_out, int out_size, void* d_ws, size_t ws_size,
                              hipStream_t stream)
{
    (void)in_sizes; (void)n_in; (void)out_size; (void)ws_size;
    const float* x   = (const float*)d_in[0];
    const float* Wq  = (const float*)d_in[1];
    const float* bq  = (const float*)d_in[2];
    const float* Wk  = (const float*)d_in[3];
    const float* bk  = (const float*)d_in[4];
    const float* Wv  = (const float*)d_in[5];
    const float* bv  = (const float*)d_in[6];
    const float* Wp  = (const float*)d_in[7];
    const float* bp  = (const float*)d_in[8];
    const float* Wr  = (const float*)d_in[9];
    const float* br  = (const float*)d_in[10];
    const float* Ws  = (const float*)d_in[11];
    const float* bs  = (const float*)d_in[12];
    const float* temperature = (const float*)d_in[13];
    const float* qe  = (const float*)d_in[14];
    float* out = (float*)d_out;

    const size_t MB = 1048576;
    unsigned short* qb   = (unsigned short*)d_ws;                     // 8 MiB (q; wpb after attn)
    unsigned short* kb   = (unsigned short*)((char*)d_ws + 8 * MB);   // 8 MiB
    unsigned short* hb   = (unsigned short*)((char*)d_ws + 16 * MB);  // 8 MiB (raw h)
    unsigned short* wqkv = (unsigned short*)((char*)d_ws + 24 * MB);  // 6 MiB
    unsigned short* wg   = (unsigned short*)((char*)d_ws + 30 * MB);  // 34 KiB
    float*          bqkv = (float*)((char*)d_ws + 30 * MB + 65536);   // 12 KiB
    float*          gbuf = (float*)((char*)d_ws + 30 * MB + 131072);  // 16 KiB
    // d_out doubles as scratch until the final GEMM:
    unsigned short* xb = (unsigned short*)d_out;                      // 8 MiB
    unsigned short* vt = xb + 4 * MB;                                 // 8 MiB V^T
    unsigned short* wpb = qb;                                         // Wp bf16 (qb dead after attn)

    dim3 blk(256);
    cvt_main<<<dim3(3605), blk, 0, stream>>>(x, Wq, Wk, Wv, Wr, Ws, bq, bk, bv,
                                             xb, wqkv, wg, bqkv);
    qkv_gemm<<<dim3(32, 24), blk, 0, stream>>>(xb, wqkv, bqkv, qb, kb, vt);
    attn_kernel<<<dim3(32, 16), blk, 0, stream>>>(qb, kb, vt, temperature, qe, hb);
    gate_g<<<dim3(256), blk, 0, stream>>>(hb, wg, br, bs, Wp, wpb, gbuf);
    gemm64_out<<<dim3(64, 16), blk, 0, stream>>>(hb, wpb, bp, gbuf, out);
}

// Round 11
// 215.389 us; speedup vs baseline: 1.0461x; 1.0034x over previous
//
#include <hip/hip_runtime.h>
#include <hip/hip_bf16.h>

typedef short s16x8 __attribute__((ext_vector_type(8)));
typedef float f32x4 __attribute__((ext_vector_type(4)));

__device__ __forceinline__ float b2f(unsigned short u) {
    union { unsigned int i; float f; } v;
    v.i = ((unsigned int)u) << 16;
    return v.f;
}
// packed fp32x2 -> bf16x2 (v_cvt_pk_bf16_f32 on gfx950); lo = a, hi = b
__device__ __forceinline__ unsigned int pkbf16(float a, float b) {
    union { __hip_bfloat162 h; unsigned int u; } v;
    v.h = __float22bfloat162_rn(make_float2(a, b));
    return v.u;
}
// raw v_exp_f32 — libm exp2f adds clamp/scale VALU (measured regression r5)
__device__ __forceinline__ float fast_exp2(float x) {
#if __has_builtin(__builtin_amdgcn_exp2f)
    return __builtin_amdgcn_exp2f(x);
#else
    return exp2f(x);
#endif
}

// async global->LDS, 16B/lane; LDS dest = wave-uniform base + lane*16
__device__ __forceinline__ void gl_lds16(const unsigned short* g, unsigned short* l) {
    __builtin_amdgcn_global_load_lds(
        (const __attribute__((address_space(1))) void*)g,
        (__attribute__((address_space(3))) void*)l, 16, 0, 0);
}

// XOR-swizzle: 16B block c of row r lives at physical block c^(r%8) (mod row width).
// NOTE (r9 post-mortem): keep Ps stores as plain b16 — DPP-paired b32 stores
// measured WORSE (conflicts 3.1e6->5.2e6, VALUBusy +12pt, attn +9us).

// ---------------------------------------------------------------------------
// Merged fp32->bf16 converts + bias pack, one launch.
// ---------------------------------------------------------------------------
__device__ __forceinline__ void cvt8(const float* __restrict__ s,
                                     unsigned short* __restrict__ d, int i) {
    const float* p = s + (size_t)i * 8;
    float4 a = *(const float4*)p;
    float4 b = *(const float4*)(p + 4);
    unsigned int u0 = pkbf16(a.x, a.y), u1 = pkbf16(a.z, a.w);
    unsigned int u2 = pkbf16(b.x, b.y), u3 = pkbf16(b.z, b.w);
    uint4 o = {u0, u1, u2, u3};
    *(uint4*)&d[(size_t)i * 8] = o;
}

__global__ __launch_bounds__(256) void cvt_main(
    const float* __restrict__ x,  const float* __restrict__ Wq,
    const float* __restrict__ Wk, const float* __restrict__ Wv,
    const float* __restrict__ Wr, const float* __restrict__ Ws,
    const float* __restrict__ bq, const float* __restrict__ bk,
    const float* __restrict__ bv,
    unsigned short* __restrict__ xb, unsigned short* __restrict__ wqkv,
    unsigned short* __restrict__ wg, float* __restrict__ bqkv)
{
    int blk = blockIdx.x, t = threadIdx.x;
    if (blk < 2048)      cvt8(x,  xb,             blk * 256 + t);
    else if (blk < 2560) cvt8(Wq, wqkv,           (blk - 2048) * 256 + t);
    else if (blk < 3072) cvt8(Wk, wqkv + 1048576, (blk - 2560) * 256 + t);
    else if (blk < 3584) cvt8(Wv, wqkv + 2097152, (blk - 3072) * 256 + t);
    else if (blk < 3592) { int i = (blk - 3584) * 256 + t; if (i < 1920) cvt8(Wr, wg, i); }
    else if (blk < 3593) { int i = t; cvt8(Ws, wg + 15360, i); }
    else {
        int i = (blk - 3593) * 256 + t;  // 0..3071
        bqkv[i] = (i < 1024) ? bq[i] : (i < 2048) ? bk[i - 1024] : bv[i - 2048];
    }
}

// ---------------------------------------------------------------------------
// QKV GEMM: C = xb[4096][1024] * Wqkv[3072][1024]^T + bias.
// 128x128 tile, BK=64, swizzled LDS + global_load_lds.
// n0<1024 -> Q; <2048 -> K; else V written transposed to Vt[b,h,d,tok].
// ---------------------------------------------------------------------------
__global__ __launch_bounds__(256) void qkv_gemm(
    const unsigned short* __restrict__ A,
    const unsigned short* __restrict__ Bw,
    const float* __restrict__ bias,
    unsigned short* __restrict__ Q, unsigned short* __restrict__ K,
    unsigned short* __restrict__ Vt)
{
    __shared__ __attribute__((aligned(16))) unsigned short As[128 * 64];
    __shared__ __attribute__((aligned(16))) unsigned short Bs[128 * 64];
    const int t = threadIdx.x;
    const int wave = t >> 6, lane = t & 63;
    const int m0 = blockIdx.x * 128, n0 = blockIdx.y * 128;
    const int wm = (wave >> 1) * 64, wn = (wave & 1) * 64;
    const int lr = lane & 15, lq = lane >> 4;
    const int srow = lane >> 3;
    const int scol = (((lane & 7) ^ srow) << 3);

    f32x4 acc[4][4];
#pragma unroll
    for (int i = 0; i < 4; ++i)
#pragma unroll
        for (int j = 0; j < 4; ++j) acc[i][j] = (f32x4){0.f, 0.f, 0.f, 0.f};

    for (int k0 = 0; k0 < 1024; k0 += 64) {
        __syncthreads();
#pragma unroll
        for (int i = 0; i < 4; ++i) {
            int rb = wave * 32 + i * 8;
            gl_lds16(&A[(size_t)(m0 + rb + srow) * 1024 + k0 + scol], &As[rb * 64]);
            gl_lds16(&Bw[(size_t)(n0 + rb + srow) * 1024 + k0 + scol], &Bs[rb * 64]);
        }
        __syncthreads();
#pragma unroll
        for (int kk = 0; kk < 64; kk += 32) {
            const int po = ((((kk >> 3) + lq) ^ (lr & 7)) << 3);
            s16x8 af[4], bf[4];
#pragma unroll
            for (int i = 0; i < 4; ++i)
                af[i] = *(const s16x8*)&As[(wm + i * 16 + lr) * 64 + po];
#pragma unroll
            for (int j = 0; j < 4; ++j)
                bf[j] = *(const s16x8*)&Bs[(wn + j * 16 + lr) * 64 + po];
#pragma unroll
            for (int i = 0; i < 4; ++i)
#pragma unroll
                for (int j = 0; j < 4; ++j)
                    acc[i][j] = __builtin_amdgcn_mfma_f32_16x16x32_bf16(af[i], bf[j], acc[i][j], 0, 0, 0);
        }
    }
    const int kind = n0 >> 10;        // 0=Q 1=K 2=V
    const int nc = n0 & 1023;
    if (kind < 2) {
        unsigned short* Cm = kind ? K : Q;
#pragma unroll
        for (int j = 0; j < 4; ++j) {
            int cl = wn + j * 16 + lr;
            float bv = bias[n0 + cl];
#pragma unroll
            for (int i = 0; i < 4; ++i) {
                int rowb = m0 + wm + i * 16 + lq * 4;
                unsigned int u0 = pkbf16(acc[i][j][0] + bv, acc[i][j][1] + bv);
                unsigned int u1 = pkbf16(acc[i][j][2] + bv, acc[i][j][3] + bv);
                Cm[(size_t)(rowb + 0) * 1024 + nc + cl] = (unsigned short)u0;
                Cm[(size_t)(rowb + 1) * 1024 + nc + cl] = (unsigned short)(u0 >> 16);
                Cm[(size_t)(rowb + 2) * 1024 + nc + cl] = (unsigned short)u1;
                Cm[(size_t)(rowb + 3) * 1024 + nc + cl] = (unsigned short)(u1 >> 16);
            }
        }
    } else {
        // V -> Vt[b,h,d,tok]: 4 consecutive tokens per lane = 8B contiguous
        const int bb = m0 >> 11;
#pragma unroll
        for (int j = 0; j < 4; ++j) {
            int col = nc + wn + j * 16 + lr;      // channel 0..1023
            int hh = col >> 6, dd = col & 63;
            float bv = bias[n0 + wn + j * 16 + lr];
#pragma unroll
            for (int i = 0; i < 4; ++i) {
                int tokb = m0 + wm + i * 16 + lq * 4;
                int tloc = tokb & 2047;
                uint2 u;
                u.x = pkbf16(acc[i][j][0] + bv, acc[i][j][1] + bv);
                u.y = pkbf16(acc[i][j][2] + bv, acc[i][j][3] + bv);
                *(uint2*)&Vt[((size_t)(bb * 16 + hh) * 64 + dd) * 2048 + tloc] = u;
            }
        }
    }
}

// ---------------------------------------------------------------------------
// Flash attention, 128-q tile, Q-fragments in registers (q-scale fused),
// 128-key staging chunks in two 64-key halves, m=0 softmax, deferred
// l-reduce, swizzled LDS, Ps wave-private with plain b16 stores.
// NEW (r11): WAVE SKEW — odd waves process halves in reverse order so that
// at any instant different waves occupy different pipes (MFMA vs VALU vs LDS)
// instead of bursting the same pipe in barrier-locked phase.
// Grid (bh=32, qtile=16): one head's q-tiles share an XCD -> K/V L2 locality.
// ---------------------------------------------------------------------------
__global__ __launch_bounds__(256) void attn_kernel(
    const unsigned short* __restrict__ Q,   // raw q [B*N][C]
    const unsigned short* __restrict__ Kb,  // [B*N][C]
    const unsigned short* __restrict__ Vt,  // [B][H][64][N]
    const float* __restrict__ temp,
    const float* __restrict__ qe,
    unsigned short* __restrict__ Hout)      // [B*N][C]
{
    __shared__ __attribute__((aligned(16))) unsigned short Ks[128 * 64];  // 16 KB (also Q staging)
    __shared__ __attribute__((aligned(16))) unsigned short Vs[64 * 128];  // 16 KB
    __shared__ __attribute__((aligned(16))) unsigned short Ps[128 * 72];  // 18 KB
    const int t = threadIdx.x, wave = t >> 6, lane = t & 63;
    const int lr = lane & 15, lq = lane >> 4;
    const int bh = blockIdx.x, b = bh >> 4, h = bh & 15;
    const int q0 = blockIdx.y * 128;
    const int srow = lane >> 3;
    const int scol = (((lane & 7) ^ srow) << 3);

    // ---- prologue: stage raw Q (swizzled) into Ks region
#pragma unroll
    for (int i = 0; i < 4; ++i) {
        int rb = wave * 32 + i * 8;
        gl_lds16(&Q[(size_t)(b * 2048 + q0 + rb + srow) * 1024 + h * 64 + scol], &Ks[rb * 64]);
    }
    __syncthreads();

    // q' = (q/||q|| + qe[h]) * softplus(temp[h]) / (8 ln2), into registers.
    float tv = temp[h];
    float sp = ((tv > 20.f) ? tv : log1pf(__expf(tv))) * 0.18033688f;
    s16x8 aq[2][2];
#pragma unroll
    for (int i = 0; i < 2; ++i) {
        float v[2][8];
        float ss = 0.f;
#pragma unroll
        for (int kk = 0; kk < 2; ++kk) {
            const int po = (((kk * 4 + lq) ^ (lr & 7)) << 3);
            s16x8 f = *(const s16x8*)&Ks[(wave * 32 + i * 16 + lr) * 64 + po];
#pragma unroll
            for (int e = 0; e < 8; ++e) {
                v[kk][e] = b2f((unsigned short)f[e]);
                ss += v[kk][e] * v[kk][e];
            }
        }
        ss += __shfl_xor(ss, 16); ss += __shfl_xor(ss, 32);
        float rn = rsqrtf(ss);
#pragma unroll
        for (int kk = 0; kk < 2; ++kk) {
            const float* qh = qe + h * 64 + kk * 32 + lq * 8;
#pragma unroll
            for (int e = 0; e < 8; e += 2) {
                unsigned int u = pkbf16((v[kk][e] * rn + qh[e]) * sp,
                                        (v[kk][e + 1] * rn + qh[e + 1]) * sp);
                aq[i][kk][e] = (short)u; aq[i][kk][e + 1] = (short)(u >> 16);
            }
        }
    }

    f32x4 accO[2][4];
#pragma unroll
    for (int i = 0; i < 2; ++i)
#pragma unroll
        for (int j = 0; j < 4; ++j) accO[i][j] = (f32x4){0.f, 0.f, 0.f, 0.f};
    float lsum[2][4] = {{0.f, 0.f, 0.f, 0.f}, {0.f, 0.f, 0.f, 0.f}};

    for (int kc = 0; kc < 2048; kc += 128) {
        __syncthreads();  // prior reads (Q-frags on iter 0 / K,V on others) done
        // stage K: 128 key-rows x 64 d (wave stages 32 rows)
#pragma unroll
        for (int i = 0; i < 4; ++i) {
            int rb = wave * 32 + i * 8;
            gl_lds16(&Kb[(size_t)(b * 2048 + kc + rb + srow) * 1024 + h * 64 + scol], &Ks[rb * 64]);
        }
        // stage V: 64 d-rows x 128 keys (wave stages 16 rows; 4 rows/instr)
#pragma unroll
        for (int i = 0; i < 4; ++i) {
            int rb = wave * 16 + i * 4;
            int vrow = rb + (lane >> 4);
            int vcb = lane & 15;
            gl_lds16(&Vt[((size_t)(b * 16 + h) * 64 + vrow) * 2048 + kc + ((vcb ^ (vrow & 7)) << 3)],
                     &Vs[rb * 128]);
        }
        __syncthreads();

#pragma unroll
        for (int hh = 0; hh < 2; ++hh) {
            const int half = hh ^ (wave & 1);   // wave skew: phase-shift odd waves
            // S = Q*K^T (32 q-rows x 64 keys per wave)
            f32x4 s[2][4];
#pragma unroll
            for (int i = 0; i < 2; ++i)
#pragma unroll
                for (int j = 0; j < 4; ++j) s[i][j] = (f32x4){0.f, 0.f, 0.f, 0.f};
#pragma unroll
            for (int kk = 0; kk < 2; ++kk) {
                const int po = (((kk * 4 + lq) ^ (lr & 7)) << 3);
                s16x8 bk[4];
#pragma unroll
                for (int j = 0; j < 4; ++j)
                    bk[j] = *(const s16x8*)&Ks[(half * 64 + j * 16 + lr) * 64 + po];
#pragma unroll
                for (int i = 0; i < 2; ++i)
#pragma unroll
                    for (int j = 0; j < 4; ++j)
                        s[i][j] = __builtin_amdgcn_mfma_f32_16x16x32_bf16(aq[i][kk], bk[j], s[i][j], 0, 0, 0);
            }

            // p = 2^s; packed bf16; plain b16 stores (r8 proven pattern)
#pragma unroll
            for (int i = 0; i < 2; ++i)
#pragma unroll
                for (int r = 0; r < 4; ++r) {
                    float p0 = fast_exp2(s[i][0][r]), p1 = fast_exp2(s[i][1][r]);
                    float p2 = fast_exp2(s[i][2][r]), p3 = fast_exp2(s[i][3][r]);
                    lsum[i][r] += (p0 + p1) + (p2 + p3);
                    unsigned int ua = pkbf16(p0, p1), ub = pkbf16(p2, p3);
                    int base = (wave * 32 + i * 16 + lq * 4 + r) * 72 + lr;
                    Ps[base]      = (unsigned short)ua;
                    Ps[base + 16] = (unsigned short)(ua >> 16);
                    Ps[base + 32] = (unsigned short)ub;
                    Ps[base + 48] = (unsigned short)(ub >> 16);
                }

            // O += P * V  (same-wave LDS ordering; no barrier)
#pragma unroll
            for (int kk = 0; kk < 2; ++kk) {
                const int vb = (((half * 8 + kk * 4 + lq) ^ (lr & 7)) << 3);
                s16x8 ap[2], bv[4];
#pragma unroll
                for (int i = 0; i < 2; ++i)
                    ap[i] = *(const s16x8*)&Ps[(wave * 32 + i * 16 + lr) * 72 + kk * 32 + lq * 8];
#pragma unroll
                for (int j = 0; j < 4; ++j)
                    bv[j] = *(const s16x8*)&Vs[(j * 16 + lr) * 128 + vb];
#pragma unroll
                for (int i = 0; i < 2; ++i)
#pragma unroll
                    for (int j = 0; j < 4; ++j)
                        accO[i][j] = __builtin_amdgcn_mfma_f32_16x16x32_bf16(ap[i], bv[j], accO[i][j], 0, 0, 0);
            }
        }
    }

#pragma unroll
    for (int i = 0; i < 2; ++i)
#pragma unroll
        for (int r = 0; r < 4; ++r) {
            float l = lsum[i][r];
            l += __shfl_xor(l, 1); l += __shfl_xor(l, 2);
            l += __shfl_xor(l, 4); l += __shfl_xor(l, 8);
            float inv = 1.f / l;
            int row = q0 + wave * 32 + i * 16 + lq * 4 + r;
            size_t ob = (size_t)(b * 2048 + row) * 1024 + h * 64 + lr;
            unsigned int u0 = pkbf16(accO[i][0][r] * inv, accO[i][1][r] * inv);
            unsigned int u1 = pkbf16(accO[i][2][r] * inv, accO[i][3][r] * inv);
            Hout[ob]      = (unsigned short)u0;
            Hout[ob + 16] = (unsigned short)(u0 >> 16);
            Hout[ob + 32] = (unsigned short)u1;
            Hout[ob + 48] = (unsigned short)(u1 >> 16);
        }
}

// ---------------------------------------------------------------------------
// gate_g: g[tok] = 2*sw0 + 6*sw1*top3sum from logits = h*Wg^T + bias.
// Side job: converts Wp fp32->bf16 into wpb (region free after attn).
// ---------------------------------------------------------------------------
__global__ __launch_bounds__(256) void gate_g(
    const unsigned short* __restrict__ Hb,   // raw h [4096][1024]
    const unsigned short* __restrict__ Wg,   // rows 0..16 bf16
    const float* __restrict__ br, const float* __restrict__ bs,
    const float* __restrict__ Wp, unsigned short* __restrict__ wpb,
    float* __restrict__ g)
{
    __shared__ __attribute__((aligned(16))) unsigned short As[4][16 * 64];
    __shared__ __attribute__((aligned(16))) unsigned short Gs[4][32 * 64];
    __shared__ float Lred[4][16][32];
    const int t = threadIdx.x, wave = t >> 6, lane = t & 63;
    const int lr = lane & 15, lq = lane >> 4;
    const int m0 = blockIdx.x * 16;
    const int srow = lane >> 3;
    const int scol = (((lane & 7) ^ srow) << 3);

    // Wp convert side-job: 512 cvt8 units per block (131072 total / 256 blocks)
    cvt8(Wp, wpb, blockIdx.x * 512 + t);
    cvt8(Wp, wpb, blockIdx.x * 512 + 256 + t);

    f32x4 acc[2];
    acc[0] = (f32x4){0.f, 0.f, 0.f, 0.f};
    acc[1] = (f32x4){0.f, 0.f, 0.f, 0.f};

    for (int k0 = wave * 64; k0 < 1024; k0 += 256) {
        gl_lds16(&Hb[(size_t)(m0 + srow) * 1024 + k0 + scol], &As[wave][0]);
        gl_lds16(&Hb[(size_t)(m0 + 8 + srow) * 1024 + k0 + scol], &As[wave][8 * 64]);
#pragma unroll
        for (int i = 0; i < 4; ++i) {
            int row = i * 8 + srow;
            int wr = (row > 16) ? 16 : row;   // clamp: no OOB
            gl_lds16(&Wg[(size_t)wr * 1024 + k0 + scol], &Gs[wave][i * 8 * 64]);
        }
        __syncthreads();   // uniform trip count across waves
#pragma unroll
        for (int kk = 0; kk < 64; kk += 32) {
            const int po = ((((kk >> 3) + lq) ^ (lr & 7)) << 3);
            s16x8 af = *(const s16x8*)&As[wave][lr * 64 + po];
#pragma unroll
            for (int j = 0; j < 2; ++j) {
                s16x8 gf = *(const s16x8*)&Gs[wave][(j * 16 + lr) * 64 + po];
                acc[j] = __builtin_amdgcn_mfma_f32_16x16x32_bf16(af, gf, acc[j], 0, 0, 0);
            }
        }
    }
#pragma unroll
    for (int j = 0; j < 2; ++j)
#pragma unroll
        for (int r = 0; r < 4; ++r)
            Lred[wave][lq * 4 + r][j * 16 + lr] = acc[j][r];
    __syncthreads();
    if (t < 16) {
        float lg[17];
#pragma unroll
        for (int j = 0; j < 17; ++j)
            lg[j] = Lred[0][t][j] + Lred[1][t][j] + Lred[2][t][j] + Lred[3][t][j]
                  + ((j < 15) ? br[j] : bs[j - 15]);
        float mx = lg[0];
#pragma unroll
        for (int j = 1; j < 15; ++j) mx = fmaxf(mx, lg[j]);
        float sum = 0.f, v1 = -1.f, v2 = -1.f, v3 = -1.f;
#pragma unroll
        for (int j = 0; j < 15; ++j) {
            float e = __expf(lg[j] - mx);
            sum += e;
            if (e > v1)      { v3 = v2; v2 = v1; v1 = e; }
            else if (e > v2) { v3 = v2; v2 = e; }
            else if (e > v3) { v3 = e; }
        }
        float tops = (v1 + v2 + v3) / sum;
        float sm = fmaxf(lg[15], lg[16]);
        float e0 = __expf(lg[15] - sm), e1 = __expf(lg[16] - sm);
        float inv = 1.f / (e0 + e1);
        g[m0 + t] = 2.f * (e0 * inv) + 6.f * (e1 * inv) * tops;
    }
}

// ---------------------------------------------------------------------------
// Out-proj GEMM: out[m][:] = g[m] * (h·Wp^T)[m][:] + bp   (row-scale commutes)
// 64x64 tile, grid 1024 = 4 blocks/CU; 2x2 waves of 32x32.
// ---------------------------------------------------------------------------
__global__ __launch_bounds__(256) void gemm64_out(
    const unsigned short* __restrict__ A,
    const unsigned short* __restrict__ Bw,
    const float* __restrict__ bias,
    const float* __restrict__ g,
    float* __restrict__ C)
{
    __shared__ __attribute__((aligned(16))) unsigned short As[64 * 64];
    __shared__ __attribute__((aligned(16))) unsigned short Bs[64 * 64];
    const int t = threadIdx.x, wave = t >> 6, lane = t & 63;
    const int lr = lane & 15, lq = lane >> 4;
    const int m0 = blockIdx.x * 64, n0 = blockIdx.y * 64;
    const int wm = (wave >> 1) * 32, wn = (wave & 1) * 32;
    const int srow = lane >> 3;
    const int scol = (((lane & 7) ^ srow) << 3);

    f32x4 acc[2][2];
#pragma unroll
    for (int i = 0; i < 2; ++i)
#pragma unroll
        for (int j = 0; j < 2; ++j) acc[i][j] = (f32x4){0.f, 0.f, 0.f, 0.f};

    for (int k0 = 0; k0 < 1024; k0 += 64) {
        __syncthreads();
#pragma unroll
        for (int i = 0; i < 2; ++i) {
            int rb = wave * 16 + i * 8;
            gl_lds16(&A[(size_t)(m0 + rb + srow) * 1024 + k0 + scol], &As[rb * 64]);
            gl_lds16(&Bw[(size_t)(n0 + rb + srow) * 1024 + k0 + scol], &Bs[rb * 64]);
        }
        __syncthreads();
#pragma unroll
        for (int kk = 0; kk < 64; kk += 32) {
            const int po = ((((kk >> 3) + lq) ^ (lr & 7)) << 3);
            s16x8 af[2], bf[2];
#pragma unroll
            for (int i = 0; i < 2; ++i)
                af[i] = *(const s16x8*)&As[(wm + i * 16 + lr) * 64 + po];
#pragma unroll
            for (int j = 0; j < 2; ++j)
                bf[j] = *(const s16x8*)&Bs[(wn + j * 16 + lr) * 64 + po];
#pragma unroll
            for (int i = 0; i < 2; ++i)
#pragma unroll
                for (int j = 0; j < 2; ++j)
                    acc[i][j] = __builtin_amdgcn_mfma_f32_16x16x32_bf16(af[i], bf[j], acc[i][j], 0, 0, 0);
        }
    }
#pragma unroll
    for (int i = 0; i < 2; ++i) {
        const float4 gi = *(const float4*)&g[m0 + wm + i * 16 + lq * 4];
        float gv[4] = {gi.x, gi.y, gi.z, gi.w};
#pragma unroll
        for (int j = 0; j < 2; ++j) {
            int col = n0 + wn + j * 16 + lr;
            float bv = bias[col];
            int rowb = m0 + wm + i * 16 + lq * 4;
#pragma unroll
            for (int r = 0; r < 4; ++r)
                C[(size_t)(rowb + r) * 1024 + col] = acc[i][j][r] * gv[r] + bv;
        }
    }
}

// ---------------------------------------------------------------------------
extern "C" void kernel_launch(void* const* d_in, const int* in_sizes, int n_in,
                              void* d_out, int out_size, void* d_ws, size_t ws_size,
                              hipStream_t stream)
{
    (void)in_sizes; (void)n_in; (void)out_size; (void)ws_size;
    const float* x   = (const float*)d_in[0];
    const float* Wq  = (const float*)d_in[1];
    const float* bq  = (const float*)d_in[2];
    const float* Wk  = (const float*)d_in[3];
    const float* bk  = (const float*)d_in[4];
    const float* Wv  = (const float*)d_in[5];
    const float* bv  = (const float*)d_in[6];
    const float* Wp  = (const float*)d_in[7];
    const float* bp  = (const float*)d_in[8];
    const float* Wr  = (const float*)d_in[9];
    const float* br  = (const float*)d_in[10];
    const float* Ws  = (const float*)d_in[11];
    const float* bs  = (const float*)d_in[12];
    const float* temperature = (const float*)d_in[13];
    const float* qe  = (const float*)d_in[14];
    float* out = (float*)d_out;

    const size_t MB = 1048576;
    unsigned short* qb   = (unsigned short*)d_ws;                     // 8 MiB (q; wpb after attn)
    unsigned short* kb   = (unsigned short*)((char*)d_ws + 8 * MB);   // 8 MiB
    unsigned short* hb   = (unsigned short*)((char*)d_ws + 16 * MB);  // 8 MiB (raw h)
    unsigned short* wqkv = (unsigned short*)((char*)d_ws + 24 * MB);  // 6 MiB
    unsigned short* wg   = (unsigned short*)((char*)d_ws + 30 * MB);  // 34 KiB
    float*          bqkv = (float*)((char*)d_ws + 30 * MB + 65536);   // 12 KiB
    float*          gbuf = (float*)((char*)d_ws + 30 * MB + 131072);  // 16 KiB
    // d_out doubles as scratch until the final GEMM:
    unsigned short* xb = (unsigned short*)d_out;                      // 8 MiB
    unsigned short* vt = xb + 4 * MB;                                 // 8 MiB V^T
    unsigned short* wpb = qb;                                         // Wp bf16 (qb dead after attn)

    dim3 blk(256);
    cvt_main<<<dim3(3605), blk, 0, stream>>>(x, Wq, Wk, Wv, Wr, Ws, bq, bk, bv,
                                             xb, wqkv, wg, bqkv);
    qkv_gemm<<<dim3(32, 24), blk, 0, stream>>>(xb, wqkv, bqkv, qb, kb, vt);
    attn_kernel<<<dim3(32, 16), blk, 0, stream>>>(qb, kb, vt, temperature, qe, hb);
    gate_g<<<dim3(256), blk, 0, stream>>>(hb, wg, br, bs, Wp, wpb, gbuf);
    gemm64_out<<<dim3(64, 16), blk, 0, stream>>>(hb, wpb, bp, gbuf, out);
}